// Round 1
// baseline (4285.625 us; speedup 1.0000x reference)
//
#include <hip/hip_runtime.h>
#include <cmath>

// Problem constants
#define B_ 32
#define N_ 64
#define M_ 64
#define C_ 64
#define C1_ 16
#define H_ 256
#define G3_ 768           // 3*H
#define INTER_ 912        // 2H + 6C + C1
#define FCIN_ 2992        // 3*INTER + H
#define RPB 16            // sequences (rows) per block in gru2d

__device__ __forceinline__ float sigmoid_f(float x) {
    return 1.0f / (1.0f + __expf(-x));
}

// ---------------------------------------------------------------------------
// Kernel 1: transpose weights.
// WT2[k][g], k in [0,320): k<256 -> Whh2[g][k]; k>=256 -> Wih2[g][k-256]
// WhhT1[k][g] = Whh1[g][k]
// ---------------------------------------------------------------------------
__global__ void transpose_kernel(const float* __restrict__ Whh2,
                                 const float* __restrict__ Wih2,
                                 const float* __restrict__ Whh1,
                                 float* __restrict__ WT2,
                                 float* __restrict__ WhhT1) {
    int idx = blockIdx.x * 256 + threadIdx.x;
    if (idx < 320 * G3_) {
        int k = idx / G3_, g = idx % G3_;
        WT2[idx] = (k < 256) ? Whh2[g * 256 + k] : Wih2[g * 64 + (k - 256)];
    }
    if (idx < 256 * G3_) {
        int k = idx / G3_, g = idx % G3_;
        WhhT1[idx] = Whh1[g * 256 + k];
    }
}

// ---------------------------------------------------------------------------
// Kernel 2: d reductions over states + x1 copy -> f[:, :, 0:400]
// block = (b, j), 64 threads (c).
// f row layout: [x1(16) | max1 | mean1 | min1 | max2 | mean2 | min2 | sd1 | sd2]
// ---------------------------------------------------------------------------
__global__ __launch_bounds__(64) void reduce_states_kernel(
        const float* __restrict__ states, const float* __restrict__ x1,
        float* __restrict__ f) {
    const int c = threadIdx.x;
    const int bj = blockIdx.x;            // b*64 + j
    const int b = bj >> 6, j = bj & 63;
    const float* p1 = states + b * 262144 + j * 64 + c;    // [b][n][j][c], n-stride 4096
    const float* p2 = states + b * 262144 + j * 4096 + c;  // [b][j][m][c], m-stride 64
    float mx1 = -1e30f, mn1 = 1e30f, sm1 = 0.f;
    float mx2 = -1e30f, mn2 = 1e30f, sm2 = 0.f;
    for (int n = 0; n < 64; ++n) {
        float v = p1[n * 4096];
        mx1 = fmaxf(mx1, v); mn1 = fminf(mn1, v); sm1 += v;
    }
    for (int m = 0; m < 64; ++m) {
        float v = p2[m * 64];
        mx2 = fmaxf(mx2, v); mn2 = fminf(mn2, v); sm2 += v;
    }
    float* fr = f + bj * INTER_;
    fr[16 + c]  = mx1;  fr[80 + c]  = sm1 * (1.f / 64.f);  fr[144 + c] = mn1;
    fr[208 + c] = mx2;  fr[272 + c] = sm2 * (1.f / 64.f);  fr[336 + c] = mn2;
    if (c < 16) fr[c] = x1[bj * 16 + c];
}

// ---------------------------------------------------------------------------
// Kernel 3: persistent 2-D GRU (both sd1 and sd2).
// 256 blocks x 256 threads. blocks 0..127 -> sd1 seqs, 128..255 -> sd2 seqs.
// Each block owns RPB=16 sequences; thread t owns hidden unit t.
// Per step: gates[r][g] = sum_k h[r][k]*Whh[g][k] + sum_k x[r][k]*Wih[g][k]
// computed via transposed weights WT[320][768] (coalesced lane loads) and
// h kept k-major in LDS (float4 broadcast reads).
// ---------------------------------------------------------------------------
__global__ __launch_bounds__(256) void gru2d_kernel(
        const float* __restrict__ states,
        const int* __restrict__ perm1, const int* __restrict__ perm2,
        const float* __restrict__ WT,      // [320][768]
        const float* __restrict__ bih, const float* __restrict__ bhh,
        float* __restrict__ f) {
    __shared__ float h_lds[256][20];   // [hidden k][row], stride 20 to tame banks
    __shared__ float x_lds[64][20];    // [input k][row]
    const int tid = threadIdx.x;
    const int blk = blockIdx.x;
    const bool sd2 = blk >= 128;
    const int sblock = (blk & 127) * RPB;

    for (int i = tid; i < 256 * RPB; i += 256) h_lds[i / RPB][i % RPB] = 0.f;
    const float bihr = bih[tid],       bhhr = bhh[tid];
    const float bihz = bih[tid + 256], bhhz = bhh[tid + 256];
    const float bihn = bih[tid + 512], bhhn = bhh[tid + 512];
    __syncthreads();

    for (int t = 0; t < 64; ++t) {
        // gather x_t for all 16 rows (transposed into LDS)
        for (int i = tid; i < 64 * RPB; i += 256) {
            int r = i >> 6, c = i & 63;
            int s = sblock + r;
            int b = s >> 6, q = s & 63;
            int src;
            if (!sd2) { int m  = perm1[q * 64 + t]; src = ((b * 64 + q) * 64 + m) * 64 + c; }
            else      { int nn = perm2[q * 64 + t]; src = ((b * 64 + nn) * 64 + q) * 64 + c; }
            x_lds[c][r] = states[src];
        }
        __syncthreads();

        float ar[RPB], az[RPB], anh[RPB], anx[RPB];
        #pragma unroll
        for (int r = 0; r < RPB; ++r) { ar[r] = 0.f; az[r] = 0.f; anh[r] = 0.f; anx[r] = 0.f; }

        const float* w = WT + tid;
        for (int k = 0; k < 256; ++k) {
            const float wr = w[k * G3_];
            const float wz = w[k * G3_ + 256];
            const float wn = w[k * G3_ + 512];
            const float4* hk = (const float4*)(&h_lds[k][0]);
            float4 hv0 = hk[0], hv1 = hk[1], hv2 = hk[2], hv3 = hk[3];
            float hv[RPB] = {hv0.x, hv0.y, hv0.z, hv0.w, hv1.x, hv1.y, hv1.z, hv1.w,
                             hv2.x, hv2.y, hv2.z, hv2.w, hv3.x, hv3.y, hv3.z, hv3.w};
            #pragma unroll
            for (int r = 0; r < RPB; ++r) {
                ar[r]  = fmaf(hv[r], wr, ar[r]);
                az[r]  = fmaf(hv[r], wz, az[r]);
                anh[r] = fmaf(hv[r], wn, anh[r]);
            }
        }
        for (int k = 0; k < 64; ++k) {
            const float wr = w[(256 + k) * G3_];
            const float wz = w[(256 + k) * G3_ + 256];
            const float wn = w[(256 + k) * G3_ + 512];
            const float4* xk = (const float4*)(&x_lds[k][0]);
            float4 xv0 = xk[0], xv1 = xk[1], xv2 = xk[2], xv3 = xk[3];
            float xv[RPB] = {xv0.x, xv0.y, xv0.z, xv0.w, xv1.x, xv1.y, xv1.z, xv1.w,
                             xv2.x, xv2.y, xv2.z, xv2.w, xv3.x, xv3.y, xv3.z, xv3.w};
            #pragma unroll
            for (int r = 0; r < RPB; ++r) {
                ar[r]  = fmaf(xv[r], wr, ar[r]);
                az[r]  = fmaf(xv[r], wz, az[r]);
                anx[r] = fmaf(xv[r], wn, anx[r]);
            }
        }
        __syncthreads();   // everyone done reading h before we overwrite it
        #pragma unroll
        for (int r = 0; r < RPB; ++r) {
            float hold = h_lds[tid][r];
            float rg = sigmoid_f(ar[r] + bihr + bhhr);
            float zg = sigmoid_f(az[r] + bihz + bhhz);
            float ng = tanhf(anx[r] + bihn + rg * (anh[r] + bhhn));
            h_lds[tid][r] = (1.f - zg) * ng + zg * hold;
        }
        __syncthreads();
    }

    // write hT into f: sd1 at col 400, sd2 at col 656
    const int off = sd2 ? 656 : 400;
    #pragma unroll
    for (int r = 0; r < RPB; ++r) {
        int s = sblock + r;   // == b*64 + (n or i)
        f[s * INTER_ + off + tid] = h_lds[tid][r];
    }
}

// ---------------------------------------------------------------------------
// Kernel 4: xw1[2048][768] = f[2048][912] @ Wih1^T + bih1   (tiled fp32 GEMM)
// grid (12, 32), 256 threads, 64x64 tile, 4x4 per thread, BK=16 (912 = 57*16)
// ---------------------------------------------------------------------------
__global__ __launch_bounds__(256) void gemm_xw1(
        const float* __restrict__ f, const float* __restrict__ Wih,
        const float* __restrict__ bih, float* __restrict__ xw) {
    __shared__ float As[64][17];
    __shared__ float Bs[64][17];
    const int tid = threadIdx.x;
    const int tn = blockIdx.x;   // gate tile 0..11
    const int tm = blockIdx.y;   // row tile 0..31
    const int tx = tid & 15, ty = tid >> 4;
    float acc[4][4] = {};
    for (int k0 = 0; k0 < INTER_; k0 += 16) {
        for (int i = tid; i < 64 * 16; i += 256) {
            int r = i >> 4, kk = i & 15;
            As[r][kk] = f[(tm * 64 + r) * INTER_ + k0 + kk];
            Bs[r][kk] = Wih[(tn * 64 + r) * INTER_ + k0 + kk];
        }
        __syncthreads();
        #pragma unroll
        for (int kk = 0; kk < 16; ++kk) {
            float a[4], bb[4];
            #pragma unroll
            for (int i = 0; i < 4; ++i) a[i] = As[ty * 4 + i][kk];
            #pragma unroll
            for (int j = 0; j < 4; ++j) bb[j] = Bs[tx * 4 + j][kk];
            #pragma unroll
            for (int i = 0; i < 4; ++i)
                #pragma unroll
                for (int j = 0; j < 4; ++j)
                    acc[i][j] = fmaf(a[i], bb[j], acc[i][j]);
        }
        __syncthreads();
    }
    #pragma unroll
    for (int i = 0; i < 4; ++i) {
        int row = tm * 64 + ty * 4 + i;
        #pragma unroll
        for (int j = 0; j < 4; ++j) {
            int col = tn * 64 + tx * 4 + j;
            xw[row * G3_ + col] = acc[i][j] + bih[col];
        }
    }
}

// ---------------------------------------------------------------------------
// Kernel 5: 1-D GRU over f (32 sequences), gi precomputed in xw1.
// block = b, thread t owns hidden unit t.
// ---------------------------------------------------------------------------
__global__ __launch_bounds__(256) void gru1d_kernel(
        const float* __restrict__ xw, const float* __restrict__ WhhT,
        const float* __restrict__ bhh, float* __restrict__ hlast) {
    __shared__ float h_lds[256];
    const int tid = threadIdx.x;
    const int b = blockIdx.x;
    h_lds[tid] = 0.f;
    const float bhr = bhh[tid], bhz = bhh[tid + 256], bhn = bhh[tid + 512];
    __syncthreads();
    for (int t = 0; t < 64; ++t) {
        const float* gi = xw + (b * 64 + t) * G3_;
        float accr = 0.f, accz = 0.f, accn = 0.f;
        for (int k = 0; k < 256; ++k) {
            float hv = h_lds[k];
            const float* row = WhhT + k * G3_;
            accr = fmaf(hv, row[tid], accr);
            accz = fmaf(hv, row[tid + 256], accz);
            accn = fmaf(hv, row[tid + 512], accn);
        }
        float rg = sigmoid_f(gi[tid] + accr + bhr);
        float zg = sigmoid_f(gi[tid + 256] + accz + bhz);
        float ng = tanhf(gi[tid + 512] + rg * (accn + bhn));
        float hold = h_lds[tid];
        __syncthreads();
        h_lds[tid] = (1.f - zg) * ng + zg * hold;
        __syncthreads();
    }
    hlast[b * 256 + tid] = h_lds[tid];
}

// ---------------------------------------------------------------------------
// Kernel 6: tail — g = [f.max(1)|f.mean(1)|f.min(1)|hlast], fc1+relu, fc2.
// block = b, 256 threads.
// ---------------------------------------------------------------------------
__global__ __launch_bounds__(256) void tail_kernel(
        const float* __restrict__ f, const float* __restrict__ hlast,
        const float* __restrict__ fc1W, const float* __restrict__ fc1b,
        const float* __restrict__ fc2W, const float* __restrict__ fc2b,
        float* __restrict__ out) {
    __shared__ float g_lds[FCIN_];
    __shared__ float red[256];
    const int tid = threadIdx.x;
    const int b = blockIdx.x;
    for (int i = tid; i < INTER_; i += 256) {
        float mx = -1e30f, mn = 1e30f, sm = 0.f;
        for (int t = 0; t < 64; ++t) {
            float v = f[(b * 64 + t) * INTER_ + i];
            mx = fmaxf(mx, v); mn = fminf(mn, v); sm += v;
        }
        g_lds[i] = mx;
        g_lds[INTER_ + i] = sm * (1.f / 64.f);
        g_lds[2 * INTER_ + i] = mn;
    }
    g_lds[3 * INTER_ + tid] = hlast[b * 256 + tid];
    __syncthreads();
    float acc = fc1b[tid];
    for (int i = 0; i < FCIN_; ++i)
        acc = fmaf(g_lds[i], fc1W[tid * FCIN_ + i], acc);
    float hv = fmaxf(acc, 0.f);
    red[tid] = hv * fc2W[tid];
    __syncthreads();
    if (tid == 0) {
        float s = fc2b[0];
        for (int i = 0; i < 256; ++i) s += red[i];
        out[b] = s;
    }
}

// ---------------------------------------------------------------------------
extern "C" void kernel_launch(void* const* d_in, const int* in_sizes, int n_in,
                              void* d_out, int out_size, void* d_ws, size_t ws_size,
                              hipStream_t stream) {
    const float* x1     = (const float*)d_in[0];
    const float* states = (const float*)d_in[1];
    const int*   perm1  = (const int*)d_in[2];
    const int*   perm2  = (const int*)d_in[3];
    const float* Wih2   = (const float*)d_in[4];
    const float* Whh2   = (const float*)d_in[5];
    const float* bih2   = (const float*)d_in[6];
    const float* bhh2   = (const float*)d_in[7];
    const float* Wih1   = (const float*)d_in[8];
    const float* Whh1   = (const float*)d_in[9];
    const float* bih1   = (const float*)d_in[10];
    const float* bhh1   = (const float*)d_in[11];
    const float* fc1W   = (const float*)d_in[12];
    const float* fc1b   = (const float*)d_in[13];
    const float* fc2W   = (const float*)d_in[14];
    const float* fc2b   = (const float*)d_in[15];
    float* out = (float*)d_out;

    float* ws    = (float*)d_ws;
    float* WT2   = ws;                         // 320*768   = 245760
    float* WhhT1 = WT2 + 320 * G3_;            // 256*768   = 196608
    float* f     = WhhT1 + 256 * G3_;          // 2048*912  = 1867776
    float* xw1   = f + 2048 * INTER_;          // 2048*768  = 1572864
    float* hlast = xw1 + 2048 * G3_;           // 32*256    = 8192

    transpose_kernel<<<dim3((320 * G3_ + 255) / 256), 256, 0, stream>>>(
        Whh2, Wih2, Whh1, WT2, WhhT1);
    reduce_states_kernel<<<dim3(2048), 64, 0, stream>>>(states, x1, f);
    gru2d_kernel<<<dim3(256), 256, 0, stream>>>(states, perm1, perm2, WT2, bih2, bhh2, f);
    gemm_xw1<<<dim3(12, 32), 256, 0, stream>>>(f, Wih1, bih1, xw1);
    gru1d_kernel<<<dim3(32), 256, 0, stream>>>(xw1, WhhT1, bhh1, hlast);
    tail_kernel<<<dim3(32), 256, 0, stream>>>(f, hlast, fc1W, fc1b, fc2W, fc2b, out);
}

// Round 2
// 2035.890 us; speedup vs baseline: 2.1050x; 2.1050x over previous
//
#include <hip/hip_runtime.h>
#include <cmath>

#define B_ 32
#define N_ 64
#define H_ 256
#define G3_ 768           // 3*H
#define INTER_ 912        // 2H + 6C + C1
#define FCIN_ 2992        // 3*INTER + H

#define PADA 264          // hA row stride (bf16 elems), 528 B: 16B-aligned, bank-shifted
#define PADX 72           // xA row stride (bf16 elems), 144 B
#define PADP 772          // preA row stride (fp32)
#define PADBN 260         // preBn row stride (fp32)

typedef __attribute__((ext_vector_type(8))) short short8;
typedef __attribute__((ext_vector_type(4))) float float4v;

__device__ __forceinline__ float sigmoid_f(float x) {
    return __fdividef(1.0f, 1.0f + __expf(-x));
}
__device__ __forceinline__ float tanh_fast(float x) {
    x = fminf(fmaxf(x, -15.f), 15.f);
    float e = __expf(2.f * x);
    return 1.f - __fdividef(2.f, e + 1.f);
}
// fp32 -> bf16 bits, round-to-nearest-even
__device__ __forceinline__ unsigned f2bf_bits(float x) {
    unsigned u = __float_as_uint(x);
    return (u + 0x7fffu + ((u >> 16) & 1u)) >> 16;
}
__device__ __forceinline__ short f2bf(float x) { return (short)f2bf_bits(x); }

// ---------------------------------------------------------------------------
// prep: (a) Bfrag bf16 fragment-major pack of gru2d weights
//       (b) WhhT1 transpose  (c) fc1Wt transpose
// Bfrag layout: [kt(10)][ntile(48)][lane(64)][j(8)] bf16, kt<8 = h-part (k=kt*32+q*8+j),
// kt>=8 = x-part. lane = (n_local) + 16*q, n = ntile*16 + n_local.
// ---------------------------------------------------------------------------
__global__ __launch_bounds__(256) void prep_kernel(
        const float* __restrict__ Whh2, const float* __restrict__ Wih2,
        const float* __restrict__ Whh1, const float* __restrict__ fc1W,
        short* __restrict__ Bfrag, float* __restrict__ WhhT1,
        float* __restrict__ fc1Wt) {
    int idx = blockIdx.x * 256 + threadIdx.x;
    if (idx < 10 * 48 * 64 * 8) {
        int j = idx & 7, lane = (idx >> 3) & 63, tile = idx >> 9;
        int nt = tile % 48, kt = tile / 48;
        int n = nt * 16 + (lane & 15);
        int kb = (lane >> 4) * 8 + j;
        float v = (kt < 8) ? Whh2[n * 256 + kt * 32 + kb]
                           : Wih2[n * 64 + (kt - 8) * 32 + kb];
        Bfrag[idx] = f2bf(v);
    }
    if (idx < 256 * G3_) {
        int k = idx / G3_, g = idx % G3_;
        WhhT1[idx] = Whh1[g * 256 + k];
    }
    if (idx < FCIN_ * 256) {
        int o = idx & 255, i = idx >> 8;
        fc1Wt[idx] = fc1W[o * FCIN_ + i];
    }
}

// ---------------------------------------------------------------------------
// reduce_states: d[] reductions + x1 copy -> f[:, 0:400]
// ---------------------------------------------------------------------------
__global__ __launch_bounds__(64) void reduce_states_kernel(
        const float* __restrict__ states, const float* __restrict__ x1,
        float* __restrict__ f) {
    const int c = threadIdx.x;
    const int bj = blockIdx.x;
    const int b = bj >> 6, j = bj & 63;
    const float* p1 = states + b * 262144 + j * 64 + c;
    const float* p2 = states + b * 262144 + j * 4096 + c;
    float mx1 = -1e30f, mn1 = 1e30f, sm1 = 0.f;
    float mx2 = -1e30f, mn2 = 1e30f, sm2 = 0.f;
    for (int n = 0; n < 64; ++n) {
        float v = p1[n * 4096];
        mx1 = fmaxf(mx1, v); mn1 = fminf(mn1, v); sm1 += v;
    }
    for (int m = 0; m < 64; ++m) {
        float v = p2[m * 64];
        mx2 = fmaxf(mx2, v); mn2 = fminf(mn2, v); sm2 += v;
    }
    float* fr = f + bj * INTER_;
    fr[16 + c]  = mx1;  fr[80 + c]  = sm1 * (1.f / 64.f);  fr[144 + c] = mn1;
    fr[208 + c] = mx2;  fr[272 + c] = sm2 * (1.f / 64.f);  fr[336 + c] = mn2;
    if (c < 16) fr[c] = x1[bj * 16 + c];
}

// ---------------------------------------------------------------------------
// gru2d via MFMA bf16. 256 blocks x 512 threads (8 waves). Block owns 16 seqs;
// wave w owns 6 N-tiles (96 gate cols). Per step: A=[16x320] bf16 (h|x),
// B streamed from L2 in fragment-major layout, D split into x-part (accA) and
// h-part (accB) so the n-gate's r*(gh_n+bhh_n) is computable.
// ---------------------------------------------------------------------------
__global__ __launch_bounds__(512) void gru2d_mfma(
        const float* __restrict__ states,
        const int* __restrict__ perm1, const int* __restrict__ perm2,
        const short* __restrict__ Bfrag,
        const float* __restrict__ bih, const float* __restrict__ bhh,
        float* __restrict__ f) {
    __shared__ short hA[16 * PADA];     // h as bf16, A-operand friendly
    __shared__ short xA[16 * PADX];     // x_t as bf16
    __shared__ float preA[16 * PADP];   // rz: full preact; n: x-part
    __shared__ float preBn[16 * PADBN]; // n: h-part
    __shared__ int perms[1024];

    const int tid = threadIdx.x;
    const int lane = tid & 63;
    const int w = tid >> 6;            // wave 0..7
    const int m = lane & 15;           // A-row / D-col index
    const int q = lane >> 4;           // quad
    const bool sd2 = blockIdx.x >= 128;
    const int sblock = (blockIdx.x & 127) * 16;

    for (int i = tid; i < 1024; i += 512) {
        int r = i >> 6, t = i & 63;
        int qq = (sblock + r) & 63;
        perms[i] = sd2 ? perm2[qq * 64 + t] : perm1[qq * 64 + t];
    }
    for (int i = tid; i < 16 * PADA; i += 512) hA[i] = 0;

    // elementwise ownership: unit u, rows mrow0..mrow0+7
    const int u = tid & 255;
    const int mrow0 = (tid >> 8) * 8;
    float hreg[8] = {0.f, 0.f, 0.f, 0.f, 0.f, 0.f, 0.f, 0.f};
    const float br  = bih[u] + bhh[u];
    const float bz  = bih[256 + u] + bhh[256 + u];
    const float bin_ = bih[512 + u];
    const float bhn  = bhh[512 + u];
    __syncthreads();

    const short8* Bf8 = (const short8*)Bfrag;

    for (int t = 0; t < 64; ++t) {
        // stage x_t (gathered rows of states) into xA as bf16
        for (int i = tid; i < 1024; i += 512) {
            int r = i >> 6, c = i & 63;
            int s = sblock + r, b = s >> 6, qq = s & 63;
            int p = perms[r * 64 + t];
            int src = sd2 ? ((b * 64 + p) * 64 + qq) * 64 + c
                          : ((b * 64 + qq) * 64 + p) * 64 + c;
            xA[r * PADX + c] = f2bf(states[src]);
        }
        __syncthreads();

        float4v accA[6], accB[6];
        #pragma unroll
        for (int ti = 0; ti < 6; ++ti) {
            accA[ti] = (float4v){0.f, 0.f, 0.f, 0.f};
            accB[ti] = (float4v){0.f, 0.f, 0.f, 0.f};
        }
        // x phase (kt = 8,9 in Bfrag)
        #pragma unroll
        for (int kt = 0; kt < 2; ++kt) {
            short8 a = *(const short8*)(xA + m * PADX + kt * 32 + q * 8);
            #pragma unroll
            for (int ti = 0; ti < 6; ++ti) {
                short8 bf = Bf8[((8 + kt) * 48 + (w * 6 + ti)) * 64 + lane];
                accA[ti] = __builtin_amdgcn_mfma_f32_16x16x32_bf16(a, bf, accA[ti], 0, 0, 0);
            }
        }
        // h phase (kt = 0..7)
        #pragma unroll
        for (int kt = 0; kt < 8; ++kt) {
            short8 a = *(const short8*)(hA + m * PADA + kt * 32 + q * 8);
            #pragma unroll
            for (int ti = 0; ti < 6; ++ti) {
                short8 bf = Bf8[(kt * 48 + (w * 6 + ti)) * 64 + lane];
                accB[ti] = __builtin_amdgcn_mfma_f32_16x16x32_bf16(a, bf, accB[ti], 0, 0, 0);
            }
        }
        // write preacts to LDS (D layout: col = lane&15, row = q*4 + reg)
        #pragma unroll
        for (int ti = 0; ti < 6; ++ti) {
            int gcol = (w * 6 + ti) * 16 + m;
            if (gcol < 512) {
                #pragma unroll
                for (int p2 = 0; p2 < 4; ++p2)
                    preA[(q * 4 + p2) * PADP + gcol] = accA[ti][p2] + accB[ti][p2];
            } else {
                #pragma unroll
                for (int p2 = 0; p2 < 4; ++p2) {
                    preA[(q * 4 + p2) * PADP + gcol] = accA[ti][p2];
                    preBn[(q * 4 + p2) * PADBN + (gcol - 512)] = accB[ti][p2];
                }
            }
        }
        __syncthreads();
        // elementwise GRU update; h stays fp32 in regs, bf16 copy to hA
        #pragma unroll
        for (int rr = 0; rr < 8; ++rr) {
            int row = mrow0 + rr;
            float gr  = preA[row * PADP + u] + br;
            float gz  = preA[row * PADP + 256 + u] + bz;
            float gnx = preA[row * PADP + 512 + u] + bin_;
            float gnh = preBn[row * PADBN + u] + bhn;
            float r_ = sigmoid_f(gr);
            float z_ = sigmoid_f(gz);
            float n_ = tanh_fast(gnx + r_ * gnh);
            float hn = (1.f - z_) * n_ + z_ * hreg[rr];
            hreg[rr] = hn;
            hA[row * PADA + u] = f2bf(hn);
        }
        __syncthreads();
    }

    const int off = sd2 ? 656 : 400;
    #pragma unroll
    for (int rr = 0; rr < 8; ++rr) {
        int s = sblock + mrow0 + rr;
        f[s * INTER_ + off + u] = hreg[rr];
    }
}

// ---------------------------------------------------------------------------
// xw1[2048][768] = f[2048][912] @ Wih1^T + bih1  (fp32 tiled GEMM)
// ---------------------------------------------------------------------------
__global__ __launch_bounds__(256) void gemm_xw1(
        const float* __restrict__ f, const float* __restrict__ Wih,
        const float* __restrict__ bih, float* __restrict__ xw) {
    __shared__ float As[64][17];
    __shared__ float Bs[64][17];
    const int tid = threadIdx.x;
    const int tn = blockIdx.x;
    const int tm = blockIdx.y;
    const int tx = tid & 15, ty = tid >> 4;
    float acc[4][4] = {};
    for (int k0 = 0; k0 < INTER_; k0 += 16) {
        for (int i = tid; i < 64 * 16; i += 256) {
            int r = i >> 4, kk = i & 15;
            As[r][kk] = f[(tm * 64 + r) * INTER_ + k0 + kk];
            Bs[r][kk] = Wih[(tn * 64 + r) * INTER_ + k0 + kk];
        }
        __syncthreads();
        #pragma unroll
        for (int kk = 0; kk < 16; ++kk) {
            float a[4], bb[4];
            #pragma unroll
            for (int i = 0; i < 4; ++i) a[i] = As[ty * 4 + i][kk];
            #pragma unroll
            for (int j = 0; j < 4; ++j) bb[j] = Bs[tx * 4 + j][kk];
            #pragma unroll
            for (int i = 0; i < 4; ++i)
                #pragma unroll
                for (int j = 0; j < 4; ++j)
                    acc[i][j] = fmaf(a[i], bb[j], acc[i][j]);
        }
        __syncthreads();
    }
    #pragma unroll
    for (int i = 0; i < 4; ++i) {
        int row = tm * 64 + ty * 4 + i;
        #pragma unroll
        for (int j = 0; j < 4; ++j) {
            int col = tn * 64 + tx * 4 + j;
            xw[row * G3_ + col] = acc[i][j] + bih[col];
        }
    }
}

// ---------------------------------------------------------------------------
// gru1d: 32 blocks x 768 threads. Thread g owns gate-col g; Whh col held as
// 128 packed bf16 pairs in VGPRs (resident across all 64 steps). h fp32 LDS.
// ---------------------------------------------------------------------------
__global__ __launch_bounds__(768) void gru1d_kernel(
        const float* __restrict__ xw, const float* __restrict__ WhhT,
        const float* __restrict__ bhh, float* __restrict__ hlast) {
    __shared__ float h_lds[256];
    __shared__ float gate[768];
    const int tid = threadIdx.x;
    const int b = blockIdx.x;

    unsigned wpk[128];
    #pragma unroll
    for (int kk = 0; kk < 128; ++kk) {
        unsigned b0 = f2bf_bits(WhhT[(2 * kk) * G3_ + tid]);
        unsigned b1 = f2bf_bits(WhhT[(2 * kk + 1) * G3_ + tid]);
        wpk[kk] = b0 | (b1 << 16);
    }
    float bhr = 0.f, bhz = 0.f, bhn = 0.f;
    if (tid < 256) {
        h_lds[tid] = 0.f;
        bhr = bhh[tid]; bhz = bhh[tid + 256]; bhn = bhh[tid + 512];
    }
    __syncthreads();

    for (int t = 0; t < 64; ++t) {
        float acc = 0.f;
        #pragma unroll
        for (int kk = 0; kk < 128; ++kk) {
            float2 hv = *(const float2*)(h_lds + 2 * kk);
            float w0 = __uint_as_float(wpk[kk] << 16);
            float w1 = __uint_as_float(wpk[kk] & 0xffff0000u);
            acc = fmaf(hv.y, w1, fmaf(hv.x, w0, acc));
        }
        gate[tid] = acc;
        __syncthreads();
        if (tid < 256) {
            const float* gi = xw + (b * 64 + t) * G3_;
            float r_ = sigmoid_f(gi[tid] + gate[tid] + bhr);
            float z_ = sigmoid_f(gi[tid + 256] + gate[tid + 256] + bhz);
            float n_ = tanh_fast(gi[tid + 512] + r_ * (gate[tid + 512] + bhn));
            h_lds[tid] = (1.f - z_) * n_ + z_ * h_lds[tid];
        }
        __syncthreads();
    }
    if (tid < 256) hlast[b * 256 + tid] = h_lds[tid];
}

// ---------------------------------------------------------------------------
// tail: g = [f.max(1)|f.mean(1)|f.min(1)|hlast], fc1+relu, fc2 (fc1Wt coalesced)
// ---------------------------------------------------------------------------
__global__ __launch_bounds__(256) void tail_kernel(
        const float* __restrict__ f, const float* __restrict__ hlast,
        const float* __restrict__ fc1Wt, const float* __restrict__ fc1b,
        const float* __restrict__ fc2W, const float* __restrict__ fc2b,
        float* __restrict__ out) {
    __shared__ float g_lds[FCIN_];
    __shared__ float red[256];
    const int tid = threadIdx.x;
    const int b = blockIdx.x;
    for (int i = tid; i < INTER_; i += 256) {
        float mx = -1e30f, mn = 1e30f, sm = 0.f;
        for (int t = 0; t < 64; ++t) {
            float v = f[(b * 64 + t) * INTER_ + i];
            mx = fmaxf(mx, v); mn = fminf(mn, v); sm += v;
        }
        g_lds[i] = mx;
        g_lds[INTER_ + i] = sm * (1.f / 64.f);
        g_lds[2 * INTER_ + i] = mn;
    }
    g_lds[3 * INTER_ + tid] = hlast[b * 256 + tid];
    __syncthreads();
    float acc = fc1b[tid];
    for (int i = 0; i < FCIN_; ++i)
        acc = fmaf(g_lds[i], fc1Wt[i * 256 + tid], acc);
    float hv = fmaxf(acc, 0.f);
    red[tid] = hv * fc2W[tid];
    __syncthreads();
    if (tid == 0) {
        float s = fc2b[0];
        for (int i = 0; i < 256; ++i) s += red[i];
        out[b] = s;
    }
}

// ---------------------------------------------------------------------------
extern "C" void kernel_launch(void* const* d_in, const int* in_sizes, int n_in,
                              void* d_out, int out_size, void* d_ws, size_t ws_size,
                              hipStream_t stream) {
    const float* x1     = (const float*)d_in[0];
    const float* states = (const float*)d_in[1];
    const int*   perm1  = (const int*)d_in[2];
    const int*   perm2  = (const int*)d_in[3];
    const float* Wih2   = (const float*)d_in[4];
    const float* Whh2   = (const float*)d_in[5];
    const float* bih2   = (const float*)d_in[6];
    const float* bhh2   = (const float*)d_in[7];
    const float* Wih1   = (const float*)d_in[8];
    const float* Whh1   = (const float*)d_in[9];
    const float* bih1   = (const float*)d_in[10];
    const float* bhh1   = (const float*)d_in[11];
    const float* fc1W   = (const float*)d_in[12];
    const float* fc1b   = (const float*)d_in[13];
    const float* fc2W   = (const float*)d_in[14];
    const float* fc2b   = (const float*)d_in[15];
    float* out = (float*)d_out;

    float* ws = (float*)d_ws;
    short* Bfrag = (short*)ws;                 // 245760 bf16 = 491520 B = 122880 floats
    float* WhhT1 = ws + 122880;                // 196608
    float* fc1Wt = WhhT1 + 256 * G3_;          // 765952
    float* f     = fc1Wt + FCIN_ * 256;        // 1867776
    float* xw1   = f + 2048 * INTER_;          // 1572864
    float* hlast = xw1 + 2048 * G3_;           // 8192

    prep_kernel<<<dim3(2992), 256, 0, stream>>>(Whh2, Wih2, Whh1, fc1W,
                                                Bfrag, WhhT1, fc1Wt);
    reduce_states_kernel<<<dim3(2048), 64, 0, stream>>>(states, x1, f);
    gru2d_mfma<<<dim3(256), 512, 0, stream>>>(states, perm1, perm2, Bfrag,
                                              bih2, bhh2, f);
    gemm_xw1<<<dim3(12, 32), 256, 0, stream>>>(f, Wih1, bih1, xw1);
    gru1d_kernel<<<dim3(32), 768, 0, stream>>>(xw1, WhhT1, bhh1, hlast);
    tail_kernel<<<dim3(32), 256, 0, stream>>>(f, hlast, fc1Wt, fc1b, fc2W, fc2b, out);
}

// Round 3
// 1355.361 us; speedup vs baseline: 3.1620x; 1.5021x over previous
//
#include <hip/hip_runtime.h>
#include <cmath>

#define B_ 32
#define N_ 64
#define H_ 256
#define G3_ 768           // 3*H
#define INTER_ 912        // 2H + 6C + C1
#define FCIN_ 2992        // 3*INTER + H

#define PADA 264          // hA row stride (bf16 elems)
#define PADX 72           // xA row stride (bf16 elems)

typedef __attribute__((ext_vector_type(8))) short short8;
typedef __attribute__((ext_vector_type(4))) float float4v;

__device__ __forceinline__ float sigmoid_f(float x) {
    return __fdividef(1.0f, 1.0f + __expf(-x));
}
__device__ __forceinline__ float tanh_fast(float x) {
    x = fminf(fmaxf(x, -15.f), 15.f);
    float e = __expf(2.f * x);
    return 1.f - __fdividef(2.f, e + 1.f);
}
__device__ __forceinline__ unsigned f2bf_bits(float x) {
    unsigned u = __float_as_uint(x);
    return (u + 0x7fffu + ((u >> 16) & 1u)) >> 16;
}
__device__ __forceinline__ short f2bf(float x) { return (short)f2bf_bits(x); }

// ---------------------------------------------------------------------------
// prep: (a) Bfrag bf16 fragment-major pack of gru2d weights  (layout verified R2)
//       (b) WhhT1 transpose  (c) fc1Wt transpose
// Bfrag: [kt(10)][ntile(48)][lane(64)][j(8)] bf16; kt<8: Whh2 k=kt*32+q*8+j,
// kt>=8: Wih2 k=(kt-8)*32+q*8+j; lane = n_local + 16*q, n = ntile*16 + n_local.
// ---------------------------------------------------------------------------
__global__ __launch_bounds__(256) void prep_kernel(
        const float* __restrict__ Whh2, const float* __restrict__ Wih2,
        const float* __restrict__ Whh1, const float* __restrict__ fc1W,
        short* __restrict__ Bfrag, float* __restrict__ WhhT1,
        float* __restrict__ fc1Wt) {
    int idx = blockIdx.x * 256 + threadIdx.x;
    if (idx < 10 * 48 * 64 * 8) {
        int j = idx & 7, lane = (idx >> 3) & 63, tile = idx >> 9;
        int nt = tile % 48, kt = tile / 48;
        int n = nt * 16 + (lane & 15);
        int kb = (lane >> 4) * 8 + j;
        float v = (kt < 8) ? Whh2[n * 256 + kt * 32 + kb]
                           : Wih2[n * 64 + (kt - 8) * 32 + kb];
        Bfrag[idx] = f2bf(v);
    }
    if (idx < 256 * G3_) {
        int k = idx / G3_, g = idx % G3_;
        WhhT1[idx] = Whh1[g * 256 + k];
    }
    if (idx < FCIN_ * 256) {
        int o = idx & 255, i = idx >> 8;
        fc1Wt[idx] = fc1W[o * FCIN_ + i];
    }
}

// ---------------------------------------------------------------------------
// reduce_states: d[] reductions + x1 copy -> f[:, 0:400]. 512 blocks x 256thr,
// each wave (64 lanes) handles one (b,j).
// ---------------------------------------------------------------------------
__global__ __launch_bounds__(256) void reduce_states_kernel(
        const float* __restrict__ states, const float* __restrict__ x1,
        float* __restrict__ f) {
    const int c = threadIdx.x & 63;
    const int bj = blockIdx.x * 4 + (threadIdx.x >> 6);
    const int b = bj >> 6, j = bj & 63;
    const float* p1 = states + b * 262144 + j * 64 + c;
    const float* p2 = states + b * 262144 + j * 4096 + c;
    float mx1 = -1e30f, mn1 = 1e30f, sm1 = 0.f;
    float mx2 = -1e30f, mn2 = 1e30f, sm2 = 0.f;
    #pragma unroll 8
    for (int n = 0; n < 64; ++n) {
        float v = p1[n * 4096];
        mx1 = fmaxf(mx1, v); mn1 = fminf(mn1, v); sm1 += v;
    }
    #pragma unroll 8
    for (int m = 0; m < 64; ++m) {
        float v = p2[m * 64];
        mx2 = fmaxf(mx2, v); mn2 = fminf(mn2, v); sm2 += v;
    }
    float* fr = f + bj * INTER_;
    fr[16 + c]  = mx1;  fr[80 + c]  = sm1 * (1.f / 64.f);  fr[144 + c] = mn1;
    fr[208 + c] = mx2;  fr[272 + c] = sm2 * (1.f / 64.f);  fr[336 + c] = mn2;
    if (c < 16) fr[c] = x1[bj * 16 + c];
}

// ---------------------------------------------------------------------------
// gru2d via MFMA bf16, B-resident. 256 blocks x 512 threads (8 waves, 2/EU).
// Block owns 16 seqs. Wave w owns ntiles {8j+w, j=0..5}:
//   j0: r(u0) j1: r(u1) j2: z(u0) j3: z(u1) j4: n(u0) j5: n(u1),
//   u0 = 16w + (lane&15), u1 = 128 + u0  -> full GRU update in registers.
// B: kt0..5 in VGPRs (36 frags), kt6..7 in LDS (96 KB, loaded once),
// kt8..9 (x-part, 12 KB/wave, L2-hot) loaded per step.
// ---------------------------------------------------------------------------
__global__ __launch_bounds__(512, 2) void gru2d_mfma(
        const float* __restrict__ states,
        const int* __restrict__ perm1, const int* __restrict__ perm2,
        const short* __restrict__ Bfrag,
        const float* __restrict__ bih, const float* __restrict__ bhh,
        float* __restrict__ f) {
    __shared__ short hA[16 * PADA];        // 8448 B
    __shared__ short xA[2][16 * PADX];     // 4608 B (double-buffered x_t)
    __shared__ short8 Blds[2 * 48 * 64];   // 98304 B: kt 6,7
    __shared__ int perms[1024];            // 4096 B

    const int tid = threadIdx.x;
    const int lane = tid & 63;
    const int w = tid >> 6;                // wave 0..7
    const int m = lane & 15;
    const int q = lane >> 4;
    const bool sd2 = blockIdx.x >= 128;
    const int sblock = (blockIdx.x & 127) * 16;

    for (int i = tid; i < 1024; i += 512) {
        int r = i >> 6, t = i & 63;
        int qq = (sblock + r) & 63;
        perms[i] = sd2 ? perm2[qq * 64 + t] : perm1[qq * 64 + t];
    }
    for (int i = tid; i < 16 * PADA; i += 512) hA[i] = 0;
    {   // fill Blds with kt 6,7 slice (contiguous in Bfrag)
        const uint4* src = (const uint4*)(Bfrag + 6 * 48 * 64 * 8);
        uint4* dst = (uint4*)Blds;
        #pragma unroll
        for (int rep = 0; rep < 12; ++rep)
            dst[tid + rep * 512] = src[tid + rep * 512];
    }

    // resident B fragments: kt 0..5, tiles 8j+w
    const short8* Bf8 = (const short8*)Bfrag;
    short8 Bres[36];
    #pragma unroll
    for (int kt = 0; kt < 6; ++kt)
        #pragma unroll
        for (int j = 0; j < 6; ++j)
            Bres[kt * 6 + j] = Bf8[(kt * 48 + 8 * j + w) * 64 + lane];

    const int u0 = 16 * w + m;
    const int u1 = 128 + u0;
    const float br0 = bih[u0] + bhh[u0],             br1 = bih[u1] + bhh[u1];
    const float bz0 = bih[256 + u0] + bhh[256 + u0], bz1 = bih[256 + u1] + bhh[256 + u1];
    const float bnx0 = bih[512 + u0], bnx1 = bih[512 + u1];
    const float bnh0 = bhh[512 + u0], bnh1 = bhh[512 + u1];

    float4v hreg0 = {0.f, 0.f, 0.f, 0.f}, hreg1 = {0.f, 0.f, 0.f, 0.f};

    // stage x for t=0
    {
        #pragma unroll
        for (int half = 0; half < 2; ++half) {
            int i = tid + half * 512;
            int r = i >> 6, c = i & 63;
            int s = sblock + r, b = s >> 6, qq = s & 63;
            int p = perms[r * 64 + 0];
            int src = sd2 ? ((b * 64 + p) * 64 + qq) * 64 + c
                          : ((b * 64 + qq) * 64 + p) * 64 + c;
            xA[0][r * PADX + c] = f2bf(states[src]);
        }
    }
    __syncthreads();

    for (int t = 0; t < 64; ++t) {
        // x-part B loads (step-invariant addresses, L2-hot)
        short8 Bx[12];
        #pragma unroll
        for (int kt = 0; kt < 2; ++kt)
            #pragma unroll
            for (int j = 0; j < 6; ++j)
                Bx[kt * 6 + j] = Bf8[((8 + kt) * 48 + 8 * j + w) * 64 + lane];

        // issue next-step x gather early (lands during MFMA phase)
        float xg0 = 0.f, xg1 = 0.f;
        int w0 = -1, w1 = -1;
        if (t + 1 < 64) {
            #pragma unroll
            for (int half = 0; half < 2; ++half) {
                int i = tid + half * 512;
                int r = i >> 6, c = i & 63;
                int s = sblock + r, b = s >> 6, qq = s & 63;
                int p = perms[r * 64 + t + 1];
                int src = sd2 ? ((b * 64 + p) * 64 + qq) * 64 + c
                              : ((b * 64 + qq) * 64 + p) * 64 + c;
                float v = states[src];
                if (half == 0) { xg0 = v; w0 = r * PADX + c; }
                else           { xg1 = v; w1 = r * PADX + c; }
            }
        }

        float4v aR0 = {0.f,0.f,0.f,0.f}, aR1 = {0.f,0.f,0.f,0.f};
        float4v aZ0 = {0.f,0.f,0.f,0.f}, aZ1 = {0.f,0.f,0.f,0.f};
        float4v aNx0 = {0.f,0.f,0.f,0.f}, aNx1 = {0.f,0.f,0.f,0.f};
        float4v aNh0 = {0.f,0.f,0.f,0.f}, aNh1 = {0.f,0.f,0.f,0.f};

        // h-phase, VGPR-resident kt 0..5
        #pragma unroll
        for (int kt = 0; kt < 6; ++kt) {
            short8 a = *(const short8*)(hA + m * PADA + kt * 32 + q * 8);
            aR0  = __builtin_amdgcn_mfma_f32_16x16x32_bf16(a, Bres[kt*6+0], aR0, 0,0,0);
            aR1  = __builtin_amdgcn_mfma_f32_16x16x32_bf16(a, Bres[kt*6+1], aR1, 0,0,0);
            aZ0  = __builtin_amdgcn_mfma_f32_16x16x32_bf16(a, Bres[kt*6+2], aZ0, 0,0,0);
            aZ1  = __builtin_amdgcn_mfma_f32_16x16x32_bf16(a, Bres[kt*6+3], aZ1, 0,0,0);
            aNh0 = __builtin_amdgcn_mfma_f32_16x16x32_bf16(a, Bres[kt*6+4], aNh0, 0,0,0);
            aNh1 = __builtin_amdgcn_mfma_f32_16x16x32_bf16(a, Bres[kt*6+5], aNh1, 0,0,0);
        }
        // h-phase, LDS-resident kt 6..7
        #pragma unroll
        for (int kt = 0; kt < 2; ++kt) {
            short8 a = *(const short8*)(hA + m * PADA + (6 + kt) * 32 + q * 8);
            short8 b0 = Blds[(kt * 48 + 8 * 0 + w) * 64 + lane];
            short8 b1 = Blds[(kt * 48 + 8 * 1 + w) * 64 + lane];
            short8 b2 = Blds[(kt * 48 + 8 * 2 + w) * 64 + lane];
            short8 b3 = Blds[(kt * 48 + 8 * 3 + w) * 64 + lane];
            short8 b4 = Blds[(kt * 48 + 8 * 4 + w) * 64 + lane];
            short8 b5 = Blds[(kt * 48 + 8 * 5 + w) * 64 + lane];
            aR0  = __builtin_amdgcn_mfma_f32_16x16x32_bf16(a, b0, aR0, 0,0,0);
            aR1  = __builtin_amdgcn_mfma_f32_16x16x32_bf16(a, b1, aR1, 0,0,0);
            aZ0  = __builtin_amdgcn_mfma_f32_16x16x32_bf16(a, b2, aZ0, 0,0,0);
            aZ1  = __builtin_amdgcn_mfma_f32_16x16x32_bf16(a, b3, aZ1, 0,0,0);
            aNh0 = __builtin_amdgcn_mfma_f32_16x16x32_bf16(a, b4, aNh0, 0,0,0);
            aNh1 = __builtin_amdgcn_mfma_f32_16x16x32_bf16(a, b5, aNh1, 0,0,0);
        }
        // x-phase, kt 8..9
        #pragma unroll
        for (int kt = 0; kt < 2; ++kt) {
            short8 a = *(const short8*)(xA[t & 1] + m * PADX + kt * 32 + q * 8);
            aR0  = __builtin_amdgcn_mfma_f32_16x16x32_bf16(a, Bx[kt*6+0], aR0, 0,0,0);
            aR1  = __builtin_amdgcn_mfma_f32_16x16x32_bf16(a, Bx[kt*6+1], aR1, 0,0,0);
            aZ0  = __builtin_amdgcn_mfma_f32_16x16x32_bf16(a, Bx[kt*6+2], aZ0, 0,0,0);
            aZ1  = __builtin_amdgcn_mfma_f32_16x16x32_bf16(a, Bx[kt*6+3], aZ1, 0,0,0);
            aNx0 = __builtin_amdgcn_mfma_f32_16x16x32_bf16(a, Bx[kt*6+4], aNx0, 0,0,0);
            aNx1 = __builtin_amdgcn_mfma_f32_16x16x32_bf16(a, Bx[kt*6+5], aNx1, 0,0,0);
        }

        // commit next-step x to the other buffer
        if (t + 1 < 64) {
            xA[(t + 1) & 1][w0] = f2bf(xg0);
            xA[(t + 1) & 1][w1] = f2bf(xg1);
        }
        __syncthreads();   // hA reads done; xA(t+1) visible

        // register-resident GRU update; write new h (bf16) for next step's A
        #pragma unroll
        for (int p = 0; p < 4; ++p) {
            int row = q * 4 + p;
            float r0 = sigmoid_f(aR0[p] + br0);
            float z0 = sigmoid_f(aZ0[p] + bz0);
            float n0 = tanh_fast(aNx0[p] + bnx0 + r0 * (aNh0[p] + bnh0));
            float h0 = (1.f - z0) * n0 + z0 * hreg0[p];
            hreg0[p] = h0;
            hA[row * PADA + u0] = f2bf(h0);
            float r1 = sigmoid_f(aR1[p] + br1);
            float z1 = sigmoid_f(aZ1[p] + bz1);
            float n1 = tanh_fast(aNx1[p] + bnx1 + r1 * (aNh1[p] + bnh1));
            float h1 = (1.f - z1) * n1 + z1 * hreg1[p];
            hreg1[p] = h1;
            hA[row * PADA + u1] = f2bf(h1);
        }
        __syncthreads();   // hA writes visible before next step's reads
    }

    const int off = sd2 ? 656 : 400;
    #pragma unroll
    for (int p = 0; p < 4; ++p) {
        int s = sblock + q * 4 + p;
        f[s * INTER_ + off + u0] = hreg0[p];
        f[s * INTER_ + off + u1] = hreg1[p];
    }
}

// ---------------------------------------------------------------------------
// xw1[2048][768] = f[2048][912] @ Wih1^T + bih1  (fp32 tiled GEMM)
// ---------------------------------------------------------------------------
__global__ __launch_bounds__(256) void gemm_xw1(
        const float* __restrict__ f, const float* __restrict__ Wih,
        const float* __restrict__ bih, float* __restrict__ xw) {
    __shared__ float As[64][17];
    __shared__ float Bs[64][17];
    const int tid = threadIdx.x;
    const int tn = blockIdx.x;
    const int tm = blockIdx.y;
    const int tx = tid & 15, ty = tid >> 4;
    float acc[4][4] = {};
    for (int k0 = 0; k0 < INTER_; k0 += 16) {
        for (int i = tid; i < 64 * 16; i += 256) {
            int r = i >> 4, kk = i & 15;
            As[r][kk] = f[(tm * 64 + r) * INTER_ + k0 + kk];
            Bs[r][kk] = Wih[(tn * 64 + r) * INTER_ + k0 + kk];
        }
        __syncthreads();
        #pragma unroll
        for (int kk = 0; kk < 16; ++kk) {
            float a[4], bb[4];
            #pragma unroll
            for (int i = 0; i < 4; ++i) a[i] = As[ty * 4 + i][kk];
            #pragma unroll
            for (int j = 0; j < 4; ++j) bb[j] = Bs[tx * 4 + j][kk];
            #pragma unroll
            for (int i = 0; i < 4; ++i)
                #pragma unroll
                for (int j = 0; j < 4; ++j)
                    acc[i][j] = fmaf(a[i], bb[j], acc[i][j]);
        }
        __syncthreads();
    }
    #pragma unroll
    for (int i = 0; i < 4; ++i) {
        int row = tm * 64 + ty * 4 + i;
        #pragma unroll
        for (int j = 0; j < 4; ++j) {
            int col = tn * 64 + tx * 4 + j;
            xw[row * G3_ + col] = acc[i][j] + bih[col];
        }
    }
}

// ---------------------------------------------------------------------------
// gru1d: 32 blocks x 768 threads; Whh col in 128 packed-bf16 VGPRs.
// ---------------------------------------------------------------------------
__global__ __launch_bounds__(768) void gru1d_kernel(
        const float* __restrict__ xw, const float* __restrict__ WhhT,
        const float* __restrict__ bhh, float* __restrict__ hlast) {
    __shared__ float h_lds[256];
    __shared__ float gate[768];
    const int tid = threadIdx.x;
    const int b = blockIdx.x;

    unsigned wpk[128];
    #pragma unroll
    for (int kk = 0; kk < 128; ++kk) {
        unsigned b0 = f2bf_bits(WhhT[(2 * kk) * G3_ + tid]);
        unsigned b1 = f2bf_bits(WhhT[(2 * kk + 1) * G3_ + tid]);
        wpk[kk] = b0 | (b1 << 16);
    }
    float bhr = 0.f, bhz = 0.f, bhn = 0.f;
    if (tid < 256) {
        h_lds[tid] = 0.f;
        bhr = bhh[tid]; bhz = bhh[tid + 256]; bhn = bhh[tid + 512];
    }
    __syncthreads();

    for (int t = 0; t < 64; ++t) {
        float acc = 0.f;
        #pragma unroll
        for (int kk = 0; kk < 128; ++kk) {
            float2 hv = *(const float2*)(h_lds + 2 * kk);
            float w0 = __uint_as_float(wpk[kk] << 16);
            float w1 = __uint_as_float(wpk[kk] & 0xffff0000u);
            acc = fmaf(hv.y, w1, fmaf(hv.x, w0, acc));
        }
        gate[tid] = acc;
        __syncthreads();
        if (tid < 256) {
            const float* gi = xw + (b * 64 + t) * G3_;
            float r_ = sigmoid_f(gi[tid] + gate[tid] + bhr);
            float z_ = sigmoid_f(gi[tid + 256] + gate[tid + 256] + bhz);
            float n_ = tanh_fast(gi[tid + 512] + r_ * (gate[tid + 512] + bhn));
            h_lds[tid] = (1.f - z_) * n_ + z_ * h_lds[tid];
        }
        __syncthreads();
    }
    if (tid < 256) hlast[b * 256 + tid] = h_lds[tid];
}

// ---------------------------------------------------------------------------
// tail: g = [f.max(1)|f.mean(1)|f.min(1)|hlast], fc1+relu, fc2
// ---------------------------------------------------------------------------
__global__ __launch_bounds__(256) void tail_kernel(
        const float* __restrict__ f, const float* __restrict__ hlast,
        const float* __restrict__ fc1Wt, const float* __restrict__ fc1b,
        const float* __restrict__ fc2W, const float* __restrict__ fc2b,
        float* __restrict__ out) {
    __shared__ float g_lds[FCIN_];
    __shared__ float red[256];
    const int tid = threadIdx.x;
    const int b = blockIdx.x;
    for (int i = tid; i < INTER_; i += 256) {
        float mx = -1e30f, mn = 1e30f, sm = 0.f;
        for (int t = 0; t < 64; ++t) {
            float v = f[(b * 64 + t) * INTER_ + i];
            mx = fmaxf(mx, v); mn = fminf(mn, v); sm += v;
        }
        g_lds[i] = mx;
        g_lds[INTER_ + i] = sm * (1.f / 64.f);
        g_lds[2 * INTER_ + i] = mn;
    }
    g_lds[3 * INTER_ + tid] = hlast[b * 256 + tid];
    __syncthreads();
    float acc = fc1b[tid];
    for (int i = 0; i < FCIN_; ++i)
        acc = fmaf(g_lds[i], fc1Wt[i * 256 + tid], acc);
    float hv = fmaxf(acc, 0.f);
    red[tid] = hv * fc2W[tid];
    __syncthreads();
    if (tid == 0) {
        float s = fc2b[0];
        for (int i = 0; i < 256; ++i) s += red[i];
        out[b] = s;
    }
}

// ---------------------------------------------------------------------------
extern "C" void kernel_launch(void* const* d_in, const int* in_sizes, int n_in,
                              void* d_out, int out_size, void* d_ws, size_t ws_size,
                              hipStream_t stream) {
    const float* x1     = (const float*)d_in[0];
    const float* states = (const float*)d_in[1];
    const int*   perm1  = (const int*)d_in[2];
    const int*   perm2  = (const int*)d_in[3];
    const float* Wih2   = (const float*)d_in[4];
    const float* Whh2   = (const float*)d_in[5];
    const float* bih2   = (const float*)d_in[6];
    const float* bhh2   = (const float*)d_in[7];
    const float* Wih1   = (const float*)d_in[8];
    const float* Whh1   = (const float*)d_in[9];
    const float* bih1   = (const float*)d_in[10];
    const float* bhh1   = (const float*)d_in[11];
    const float* fc1W   = (const float*)d_in[12];
    const float* fc1b   = (const float*)d_in[13];
    const float* fc2W   = (const float*)d_in[14];
    const float* fc2b   = (const float*)d_in[15];
    float* out = (float*)d_out;

    float* ws = (float*)d_ws;
    short* Bfrag = (short*)ws;                 // 245760 bf16 = 122880 floats
    float* WhhT1 = ws + 122880;                // 196608
    float* fc1Wt = WhhT1 + 256 * G3_;          // 765952
    float* f     = fc1Wt + FCIN_ * 256;        // 1867776
    float* xw1   = f + 2048 * INTER_;          // 1572864
    float* hlast = xw1 + 2048 * G3_;           // 8192

    prep_kernel<<<dim3(2992), 256, 0, stream>>>(Whh2, Wih2, Whh1, fc1W,
                                                Bfrag, WhhT1, fc1Wt);
    reduce_states_kernel<<<dim3(512), 256, 0, stream>>>(states, x1, f);
    gru2d_mfma<<<dim3(256), 512, 0, stream>>>(states, perm1, perm2, Bfrag,
                                              bih2, bhh2, f);
    gemm_xw1<<<dim3(12, 32), 256, 0, stream>>>(f, Wih1, bih1, xw1);
    gru1d_kernel<<<dim3(32), 768, 0, stream>>>(xw1, WhhT1, bhh1, hlast);
    tail_kernel<<<dim3(32), 256, 0, stream>>>(f, hlast, fc1Wt, fc1b, fc2W, fc2b, out);
}

// Round 4
// 789.842 us; speedup vs baseline: 5.4259x; 1.7160x over previous
//
#include <hip/hip_runtime.h>
#include <cmath>

#define B_ 32
#define N_ 64
#define H_ 256
#define G3_ 768           // 3*H
#define INTER_ 912        // 2H + 6C + C1
#define FCIN_ 2992        // 3*INTER + H

#define PADA 264          // hA row stride (bf16 elems)
#define PADX 72           // xA row stride (bf16 elems)

typedef __attribute__((ext_vector_type(8))) short short8;
typedef __attribute__((ext_vector_type(4))) float float4v;

__device__ __forceinline__ float sigmoid_f(float x) {
    return __fdividef(1.0f, 1.0f + __expf(-x));
}
__device__ __forceinline__ float tanh_fast(float x) {
    x = fminf(fmaxf(x, -15.f), 15.f);
    float e = __expf(2.f * x);
    return 1.f - __fdividef(2.f, e + 1.f);
}
__device__ __forceinline__ unsigned f2bf_bits(float x) {
    unsigned u = __float_as_uint(x);
    return (u + 0x7fffu + ((u >> 16) & 1u)) >> 16;
}
__device__ __forceinline__ short f2bf(float x) { return (short)f2bf_bits(x); }

// ---------------------------------------------------------------------------
// prep: (a) Bfrag  = gru2d weights, fragment-major bf16 (layout verified R2)
//       (b) Bfrag1 = gru1d Whh, same fragment-major pack (8 kt)
//       (c) fc1Wt transpose
// Fragment layout: [kt][ntile(48)][lane(64)][j(8)] bf16; value = W[n][k] with
// n = ntile*16 + (lane&15), k = kt*32 + (lane>>4)*8 + j.
// ---------------------------------------------------------------------------
__global__ __launch_bounds__(256) void prep_kernel(
        const float* __restrict__ Whh2, const float* __restrict__ Wih2,
        const float* __restrict__ Whh1, const float* __restrict__ fc1W,
        short* __restrict__ Bfrag, short* __restrict__ Bfrag1,
        float* __restrict__ fc1Wt) {
    int idx = blockIdx.x * 256 + threadIdx.x;
    if (idx < 10 * 48 * 64 * 8) {
        int j = idx & 7, lane = (idx >> 3) & 63, tile = idx >> 9;
        int nt = tile % 48, kt = tile / 48;
        int n = nt * 16 + (lane & 15);
        int kb = (lane >> 4) * 8 + j;
        float v = (kt < 8) ? Whh2[n * 256 + kt * 32 + kb]
                           : Wih2[n * 64 + (kt - 8) * 32 + kb];
        Bfrag[idx] = f2bf(v);
    }
    if (idx < 8 * 48 * 64 * 8) {
        int j = idx & 7, lane = (idx >> 3) & 63, tile = idx >> 9;
        int nt = tile % 48, kt = tile / 48;
        int n = nt * 16 + (lane & 15);
        int k = kt * 32 + (lane >> 4) * 8 + j;
        Bfrag1[idx] = f2bf(Whh1[n * 256 + k]);
    }
    if (idx < FCIN_ * 256) {
        int o = idx & 255, i = idx >> 8;
        fc1Wt[idx] = fc1W[o * FCIN_ + i];
    }
}

// ---------------------------------------------------------------------------
// reduce_states: d[] reductions + x1 copy -> f[:, 0:400]
// ---------------------------------------------------------------------------
__global__ __launch_bounds__(256) void reduce_states_kernel(
        const float* __restrict__ states, const float* __restrict__ x1,
        float* __restrict__ f) {
    const int c = threadIdx.x & 63;
    const int bj = blockIdx.x * 4 + (threadIdx.x >> 6);
    const int b = bj >> 6, j = bj & 63;
    const float* p1 = states + b * 262144 + j * 64 + c;
    const float* p2 = states + b * 262144 + j * 4096 + c;
    float mx1 = -1e30f, mn1 = 1e30f, sm1 = 0.f;
    float mx2 = -1e30f, mn2 = 1e30f, sm2 = 0.f;
    #pragma unroll 8
    for (int n = 0; n < 64; ++n) {
        float v = p1[n * 4096];
        mx1 = fmaxf(mx1, v); mn1 = fminf(mn1, v); sm1 += v;
    }
    #pragma unroll 8
    for (int m = 0; m < 64; ++m) {
        float v = p2[m * 64];
        mx2 = fmaxf(mx2, v); mn2 = fminf(mn2, v); sm2 += v;
    }
    float* fr = f + bj * INTER_;
    fr[16 + c]  = mx1;  fr[80 + c]  = sm1 * (1.f / 64.f);  fr[144 + c] = mn1;
    fr[208 + c] = mx2;  fr[272 + c] = sm2 * (1.f / 64.f);  fr[336 + c] = mn2;
    if (c < 16) fr[c] = x1[bj * 16 + c];
}

// ---------------------------------------------------------------------------
// gru2d via MFMA bf16, B-resident (unchanged from R3 — verified).
// ---------------------------------------------------------------------------
__global__ __launch_bounds__(512, 2) void gru2d_mfma(
        const float* __restrict__ states,
        const int* __restrict__ perm1, const int* __restrict__ perm2,
        const short* __restrict__ Bfrag,
        const float* __restrict__ bih, const float* __restrict__ bhh,
        float* __restrict__ f) {
    __shared__ short hA[16 * PADA];
    __shared__ short xA[2][16 * PADX];
    __shared__ short8 Blds[2 * 48 * 64];
    __shared__ int perms[1024];

    const int tid = threadIdx.x;
    const int lane = tid & 63;
    const int w = tid >> 6;
    const int m = lane & 15;
    const int q = lane >> 4;
    const bool sd2 = blockIdx.x >= 128;
    const int sblock = (blockIdx.x & 127) * 16;

    for (int i = tid; i < 1024; i += 512) {
        int r = i >> 6, t = i & 63;
        int qq = (sblock + r) & 63;
        perms[i] = sd2 ? perm2[qq * 64 + t] : perm1[qq * 64 + t];
    }
    for (int i = tid; i < 16 * PADA; i += 512) hA[i] = 0;
    {
        const uint4* src = (const uint4*)(Bfrag + 6 * 48 * 64 * 8);
        uint4* dst = (uint4*)Blds;
        #pragma unroll
        for (int rep = 0; rep < 12; ++rep)
            dst[tid + rep * 512] = src[tid + rep * 512];
    }

    const short8* Bf8 = (const short8*)Bfrag;
    short8 Bres[36];
    #pragma unroll
    for (int kt = 0; kt < 6; ++kt)
        #pragma unroll
        for (int j = 0; j < 6; ++j)
            Bres[kt * 6 + j] = Bf8[(kt * 48 + 8 * j + w) * 64 + lane];

    const int u0 = 16 * w + m;
    const int u1 = 128 + u0;
    const float br0 = bih[u0] + bhh[u0],             br1 = bih[u1] + bhh[u1];
    const float bz0 = bih[256 + u0] + bhh[256 + u0], bz1 = bih[256 + u1] + bhh[256 + u1];
    const float bnx0 = bih[512 + u0], bnx1 = bih[512 + u1];
    const float bnh0 = bhh[512 + u0], bnh1 = bhh[512 + u1];

    float4v hreg0 = {0.f, 0.f, 0.f, 0.f}, hreg1 = {0.f, 0.f, 0.f, 0.f};

    {
        #pragma unroll
        for (int half = 0; half < 2; ++half) {
            int i = tid + half * 512;
            int r = i >> 6, c = i & 63;
            int s = sblock + r, b = s >> 6, qq = s & 63;
            int p = perms[r * 64 + 0];
            int src = sd2 ? ((b * 64 + p) * 64 + qq) * 64 + c
                          : ((b * 64 + qq) * 64 + p) * 64 + c;
            xA[0][r * PADX + c] = f2bf(states[src]);
        }
    }
    __syncthreads();

    for (int t = 0; t < 64; ++t) {
        short8 Bx[12];
        #pragma unroll
        for (int kt = 0; kt < 2; ++kt)
            #pragma unroll
            for (int j = 0; j < 6; ++j)
                Bx[kt * 6 + j] = Bf8[((8 + kt) * 48 + 8 * j + w) * 64 + lane];

        float xg0 = 0.f, xg1 = 0.f;
        int w0 = -1, w1 = -1;
        if (t + 1 < 64) {
            #pragma unroll
            for (int half = 0; half < 2; ++half) {
                int i = tid + half * 512;
                int r = i >> 6, c = i & 63;
                int s = sblock + r, b = s >> 6, qq = s & 63;
                int p = perms[r * 64 + t + 1];
                int src = sd2 ? ((b * 64 + p) * 64 + qq) * 64 + c
                              : ((b * 64 + qq) * 64 + p) * 64 + c;
                float v = states[src];
                if (half == 0) { xg0 = v; w0 = r * PADX + c; }
                else           { xg1 = v; w1 = r * PADX + c; }
            }
        }

        float4v aR0 = {0.f,0.f,0.f,0.f}, aR1 = {0.f,0.f,0.f,0.f};
        float4v aZ0 = {0.f,0.f,0.f,0.f}, aZ1 = {0.f,0.f,0.f,0.f};
        float4v aNx0 = {0.f,0.f,0.f,0.f}, aNx1 = {0.f,0.f,0.f,0.f};
        float4v aNh0 = {0.f,0.f,0.f,0.f}, aNh1 = {0.f,0.f,0.f,0.f};

        #pragma unroll
        for (int kt = 0; kt < 6; ++kt) {
            short8 a = *(const short8*)(hA + m * PADA + kt * 32 + q * 8);
            aR0  = __builtin_amdgcn_mfma_f32_16x16x32_bf16(a, Bres[kt*6+0], aR0, 0,0,0);
            aR1  = __builtin_amdgcn_mfma_f32_16x16x32_bf16(a, Bres[kt*6+1], aR1, 0,0,0);
            aZ0  = __builtin_amdgcn_mfma_f32_16x16x32_bf16(a, Bres[kt*6+2], aZ0, 0,0,0);
            aZ1  = __builtin_amdgcn_mfma_f32_16x16x32_bf16(a, Bres[kt*6+3], aZ1, 0,0,0);
            aNh0 = __builtin_amdgcn_mfma_f32_16x16x32_bf16(a, Bres[kt*6+4], aNh0, 0,0,0);
            aNh1 = __builtin_amdgcn_mfma_f32_16x16x32_bf16(a, Bres[kt*6+5], aNh1, 0,0,0);
        }
        #pragma unroll
        for (int kt = 0; kt < 2; ++kt) {
            short8 a = *(const short8*)(hA + m * PADA + (6 + kt) * 32 + q * 8);
            short8 b0 = Blds[(kt * 48 + 8 * 0 + w) * 64 + lane];
            short8 b1 = Blds[(kt * 48 + 8 * 1 + w) * 64 + lane];
            short8 b2 = Blds[(kt * 48 + 8 * 2 + w) * 64 + lane];
            short8 b3 = Blds[(kt * 48 + 8 * 3 + w) * 64 + lane];
            short8 b4 = Blds[(kt * 48 + 8 * 4 + w) * 64 + lane];
            short8 b5 = Blds[(kt * 48 + 8 * 5 + w) * 64 + lane];
            aR0  = __builtin_amdgcn_mfma_f32_16x16x32_bf16(a, b0, aR0, 0,0,0);
            aR1  = __builtin_amdgcn_mfma_f32_16x16x32_bf16(a, b1, aR1, 0,0,0);
            aZ0  = __builtin_amdgcn_mfma_f32_16x16x32_bf16(a, b2, aZ0, 0,0,0);
            aZ1  = __builtin_amdgcn_mfma_f32_16x16x32_bf16(a, b3, aZ1, 0,0,0);
            aNh0 = __builtin_amdgcn_mfma_f32_16x16x32_bf16(a, b4, aNh0, 0,0,0);
            aNh1 = __builtin_amdgcn_mfma_f32_16x16x32_bf16(a, b5, aNh1, 0,0,0);
        }
        #pragma unroll
        for (int kt = 0; kt < 2; ++kt) {
            short8 a = *(const short8*)(xA[t & 1] + m * PADX + kt * 32 + q * 8);
            aR0  = __builtin_amdgcn_mfma_f32_16x16x32_bf16(a, Bx[kt*6+0], aR0, 0,0,0);
            aR1  = __builtin_amdgcn_mfma_f32_16x16x32_bf16(a, Bx[kt*6+1], aR1, 0,0,0);
            aZ0  = __builtin_amdgcn_mfma_f32_16x16x32_bf16(a, Bx[kt*6+2], aZ0, 0,0,0);
            aZ1  = __builtin_amdgcn_mfma_f32_16x16x32_bf16(a, Bx[kt*6+3], aZ1, 0,0,0);
            aNx0 = __builtin_amdgcn_mfma_f32_16x16x32_bf16(a, Bx[kt*6+4], aNx0, 0,0,0);
            aNx1 = __builtin_amdgcn_mfma_f32_16x16x32_bf16(a, Bx[kt*6+5], aNx1, 0,0,0);
        }

        if (t + 1 < 64) {
            xA[(t + 1) & 1][w0] = f2bf(xg0);
            xA[(t + 1) & 1][w1] = f2bf(xg1);
        }
        __syncthreads();

        #pragma unroll
        for (int p = 0; p < 4; ++p) {
            int row = q * 4 + p;
            float r0 = sigmoid_f(aR0[p] + br0);
            float z0 = sigmoid_f(aZ0[p] + bz0);
            float n0 = tanh_fast(aNx0[p] + bnx0 + r0 * (aNh0[p] + bnh0));
            float h0 = (1.f - z0) * n0 + z0 * hreg0[p];
            hreg0[p] = h0;
            hA[row * PADA + u0] = f2bf(h0);
            float r1 = sigmoid_f(aR1[p] + br1);
            float z1 = sigmoid_f(aZ1[p] + bz1);
            float n1 = tanh_fast(aNx1[p] + bnx1 + r1 * (aNh1[p] + bnh1));
            float h1 = (1.f - z1) * n1 + z1 * hreg1[p];
            hreg1[p] = h1;
            hA[row * PADA + u1] = f2bf(h1);
        }
        __syncthreads();
    }

    const int off = sd2 ? 656 : 400;
    #pragma unroll
    for (int p = 0; p < 4; ++p) {
        int s = sblock + q * 4 + p;
        f[s * INTER_ + off + u0] = hreg0[p];
        f[s * INTER_ + off + u1] = hreg1[p];
    }
}

// ---------------------------------------------------------------------------
// xw1[2048][768] = f[2048][912] @ Wih1^T + bih1  (fp32 tiled GEMM)
// ---------------------------------------------------------------------------
__global__ __launch_bounds__(256) void gemm_xw1(
        const float* __restrict__ f, const float* __restrict__ Wih,
        const float* __restrict__ bih, float* __restrict__ xw) {
    __shared__ float As[64][17];
    __shared__ float Bs[64][17];
    const int tid = threadIdx.x;
    const int tn = blockIdx.x;
    const int tm = blockIdx.y;
    const int tx = tid & 15, ty = tid >> 4;
    float acc[4][4] = {};
    for (int k0 = 0; k0 < INTER_; k0 += 16) {
        for (int i = tid; i < 64 * 16; i += 256) {
            int r = i >> 4, kk = i & 15;
            As[r][kk] = f[(tm * 64 + r) * INTER_ + k0 + kk];
            Bs[r][kk] = Wih[(tn * 64 + r) * INTER_ + k0 + kk];
        }
        __syncthreads();
        #pragma unroll
        for (int kk = 0; kk < 16; ++kk) {
            float a[4], bb[4];
            #pragma unroll
            for (int i = 0; i < 4; ++i) a[i] = As[ty * 4 + i][kk];
            #pragma unroll
            for (int j = 0; j < 4; ++j) bb[j] = Bs[tx * 4 + j][kk];
            #pragma unroll
            for (int i = 0; i < 4; ++i)
                #pragma unroll
                for (int j = 0; j < 4; ++j)
                    acc[i][j] = fmaf(a[i], bb[j], acc[i][j]);
        }
        __syncthreads();
    }
    #pragma unroll
    for (int i = 0; i < 4; ++i) {
        int row = tm * 64 + ty * 4 + i;
        #pragma unroll
        for (int j = 0; j < 4; ++j) {
            int col = tn * 64 + tx * 4 + j;
            xw[row * G3_ + col] = acc[i][j] + bih[col];
        }
    }
}

// ---------------------------------------------------------------------------
// gru1d via MFMA bf16 (gru2d structure). 2 blocks x 512 threads; block owns
// 16 sequences. gi (x-part incl. bih) precomputed in xw1, prefetched to VGPRs.
// B: kt0..5 VGPR-resident, kt6..7 in LDS. Wave w tiles {8j+w}: j=0,1 -> r(u0,u1),
// j=2,3 -> z, j=4,5 -> gh_n. Full GRU update in registers.
// ---------------------------------------------------------------------------
__global__ __launch_bounds__(512, 2) void gru1d_mfma(
        const float* __restrict__ xw, const short* __restrict__ Bfrag1,
        const float* __restrict__ bhh, float* __restrict__ hlast) {
    __shared__ short hA[16 * PADA];
    __shared__ short8 Blds[2 * 48 * 64];   // kt 6,7

    const int tid = threadIdx.x;
    const int lane = tid & 63;
    const int w = tid >> 6;
    const int m = lane & 15;
    const int q = lane >> 4;
    const int sblock = blockIdx.x * 16;

    for (int i = tid; i < 16 * PADA; i += 512) hA[i] = 0;
    {
        const uint4* src = (const uint4*)(Bfrag1 + 6 * 48 * 64 * 8);
        uint4* dst = (uint4*)Blds;
        #pragma unroll
        for (int rep = 0; rep < 12; ++rep)
            dst[tid + rep * 512] = src[tid + rep * 512];
    }
    const short8* Bf8 = (const short8*)Bfrag1;
    short8 Bres[36];
    #pragma unroll
    for (int kt = 0; kt < 6; ++kt)
        #pragma unroll
        for (int j = 0; j < 6; ++j)
            Bres[kt * 6 + j] = Bf8[(kt * 48 + 8 * j + w) * 64 + lane];

    const int u0 = 16 * w + m;
    const int u1 = 128 + u0;
    const float br0 = bhh[u0],       br1 = bhh[u1];
    const float bz0 = bhh[256 + u0], bz1 = bhh[256 + u1];
    const float bn0 = bhh[512 + u0], bn1 = bhh[512 + u1];

    float4v hreg0 = {0.f, 0.f, 0.f, 0.f}, hreg1 = {0.f, 0.f, 0.f, 0.f};
    __syncthreads();

    for (int t = 0; t < 64; ++t) {
        // prefetch gi for this step (L2-hot; hidden under MFMAs)
        float giR0[4], giR1[4], giZ0[4], giZ1[4], giN0[4], giN1[4];
        #pragma unroll
        for (int p = 0; p < 4; ++p) {
            const float* gr = xw + ((sblock + q * 4 + p) * 64 + t) * G3_;
            giR0[p] = gr[u0];        giR1[p] = gr[u1];
            giZ0[p] = gr[256 + u0];  giZ1[p] = gr[256 + u1];
            giN0[p] = gr[512 + u0];  giN1[p] = gr[512 + u1];
        }

        float4v aR0 = {0.f,0.f,0.f,0.f}, aR1 = {0.f,0.f,0.f,0.f};
        float4v aZ0 = {0.f,0.f,0.f,0.f}, aZ1 = {0.f,0.f,0.f,0.f};
        float4v aN0 = {0.f,0.f,0.f,0.f}, aN1 = {0.f,0.f,0.f,0.f};

        #pragma unroll
        for (int kt = 0; kt < 6; ++kt) {
            short8 a = *(const short8*)(hA + m * PADA + kt * 32 + q * 8);
            aR0 = __builtin_amdgcn_mfma_f32_16x16x32_bf16(a, Bres[kt*6+0], aR0, 0,0,0);
            aR1 = __builtin_amdgcn_mfma_f32_16x16x32_bf16(a, Bres[kt*6+1], aR1, 0,0,0);
            aZ0 = __builtin_amdgcn_mfma_f32_16x16x32_bf16(a, Bres[kt*6+2], aZ0, 0,0,0);
            aZ1 = __builtin_amdgcn_mfma_f32_16x16x32_bf16(a, Bres[kt*6+3], aZ1, 0,0,0);
            aN0 = __builtin_amdgcn_mfma_f32_16x16x32_bf16(a, Bres[kt*6+4], aN0, 0,0,0);
            aN1 = __builtin_amdgcn_mfma_f32_16x16x32_bf16(a, Bres[kt*6+5], aN1, 0,0,0);
        }
        #pragma unroll
        for (int kt = 0; kt < 2; ++kt) {
            short8 a = *(const short8*)(hA + m * PADA + (6 + kt) * 32 + q * 8);
            short8 b0 = Blds[(kt * 48 + 8 * 0 + w) * 64 + lane];
            short8 b1 = Blds[(kt * 48 + 8 * 1 + w) * 64 + lane];
            short8 b2 = Blds[(kt * 48 + 8 * 2 + w) * 64 + lane];
            short8 b3 = Blds[(kt * 48 + 8 * 3 + w) * 64 + lane];
            short8 b4 = Blds[(kt * 48 + 8 * 4 + w) * 64 + lane];
            short8 b5 = Blds[(kt * 48 + 8 * 5 + w) * 64 + lane];
            aR0 = __builtin_amdgcn_mfma_f32_16x16x32_bf16(a, b0, aR0, 0,0,0);
            aR1 = __builtin_amdgcn_mfma_f32_16x16x32_bf16(a, b1, aR1, 0,0,0);
            aZ0 = __builtin_amdgcn_mfma_f32_16x16x32_bf16(a, b2, aZ0, 0,0,0);
            aZ1 = __builtin_amdgcn_mfma_f32_16x16x32_bf16(a, b3, aZ1, 0,0,0);
            aN0 = __builtin_amdgcn_mfma_f32_16x16x32_bf16(a, b4, aN0, 0,0,0);
            aN1 = __builtin_amdgcn_mfma_f32_16x16x32_bf16(a, b5, aN1, 0,0,0);
        }
        __syncthreads();   // hA reads done

        #pragma unroll
        for (int p = 0; p < 4; ++p) {
            int row = q * 4 + p;
            float r0 = sigmoid_f(giR0[p] + aR0[p] + br0);
            float z0 = sigmoid_f(giZ0[p] + aZ0[p] + bz0);
            float n0 = tanh_fast(giN0[p] + r0 * (aN0[p] + bn0));
            float h0 = (1.f - z0) * n0 + z0 * hreg0[p];
            hreg0[p] = h0;
            hA[row * PADA + u0] = f2bf(h0);
            float r1 = sigmoid_f(giR1[p] + aR1[p] + br1);
            float z1 = sigmoid_f(giZ1[p] + aZ1[p] + bz1);
            float n1 = tanh_fast(giN1[p] + r1 * (aN1[p] + bn1));
            float h1 = (1.f - z1) * n1 + z1 * hreg1[p];
            hreg1[p] = h1;
            hA[row * PADA + u1] = f2bf(h1);
        }
        __syncthreads();
    }

    #pragma unroll
    for (int p = 0; p < 4; ++p) {
        int s = sblock + q * 4 + p;
        hlast[s * 256 + u0] = hreg0[p];
        hlast[s * 256 + u1] = hreg1[p];
    }
}

// ---------------------------------------------------------------------------
// tail: g = [f.max(1)|f.mean(1)|f.min(1)|hlast], fc1+relu, fc2
// ---------------------------------------------------------------------------
__global__ __launch_bounds__(256) void tail_kernel(
        const float* __restrict__ f, const float* __restrict__ hlast,
        const float* __restrict__ fc1Wt, const float* __restrict__ fc1b,
        const float* __restrict__ fc2W, const float* __restrict__ fc2b,
        float* __restrict__ out) {
    __shared__ float g_lds[FCIN_];
    __shared__ float red[256];
    const int tid = threadIdx.x;
    const int b = blockIdx.x;
    for (int i = tid; i < INTER_; i += 256) {
        float mx = -1e30f, mn = 1e30f, sm = 0.f;
        for (int t = 0; t < 64; ++t) {
            float v = f[(b * 64 + t) * INTER_ + i];
            mx = fmaxf(mx, v); mn = fminf(mn, v); sm += v;
        }
        g_lds[i] = mx;
        g_lds[INTER_ + i] = sm * (1.f / 64.f);
        g_lds[2 * INTER_ + i] = mn;
    }
    g_lds[3 * INTER_ + tid] = hlast[b * 256 + tid];
    __syncthreads();
    float acc = fc1b[tid];
    for (int i = 0; i < FCIN_; ++i)
        acc = fmaf(g_lds[i], fc1Wt[i * 256 + tid], acc);
    float hv = fmaxf(acc, 0.f);
    red[tid] = hv * fc2W[tid];
    __syncthreads();
    if (tid == 0) {
        float s = fc2b[0];
        for (int i = 0; i < 256; ++i) s += red[i];
        out[b] = s;
    }
}

// ---------------------------------------------------------------------------
extern "C" void kernel_launch(void* const* d_in, const int* in_sizes, int n_in,
                              void* d_out, int out_size, void* d_ws, size_t ws_size,
                              hipStream_t stream) {
    const float* x1     = (const float*)d_in[0];
    const float* states = (const float*)d_in[1];
    const int*   perm1  = (const int*)d_in[2];
    const int*   perm2  = (const int*)d_in[3];
    const float* Wih2   = (const float*)d_in[4];
    const float* Whh2   = (const float*)d_in[5];
    const float* bih2   = (const float*)d_in[6];
    const float* bhh2   = (const float*)d_in[7];
    const float* Wih1   = (const float*)d_in[8];
    const float* Whh1   = (const float*)d_in[9];
    const float* bih1   = (const float*)d_in[10];
    const float* bhh1   = (const float*)d_in[11];
    const float* fc1W   = (const float*)d_in[12];
    const float* fc1b   = (const float*)d_in[13];
    const float* fc2W   = (const float*)d_in[14];
    const float* fc2b   = (const float*)d_in[15];
    float* out = (float*)d_out;

    float* ws = (float*)d_ws;
    short* Bfrag  = (short*)ws;                 // 245760 bf16 -> 122880 floats
    short* Bfrag1 = (short*)(ws + 122880);      // 196608 bf16 -> 98304 floats
    float* fc1Wt  = ws + 122880 + 98304;        // 765952
    float* f      = fc1Wt + FCIN_ * 256;        // 1867776
    float* xw1    = f + 2048 * INTER_;          // 1572864
    float* hlast  = xw1 + 2048 * G3_;           // 8192

    prep_kernel<<<dim3(2992), 256, 0, stream>>>(Whh2, Wih2, Whh1, fc1W,
                                                Bfrag, Bfrag1, fc1Wt);
    reduce_states_kernel<<<dim3(512), 256, 0, stream>>>(states, x1, f);
    gru2d_mfma<<<dim3(256), 512, 0, stream>>>(states, perm1, perm2, Bfrag,
                                              bih2, bhh2, f);
    gemm_xw1<<<dim3(12, 32), 256, 0, stream>>>(f, Wih1, bih1, xw1);
    gru1d_mfma<<<dim3(2), 512, 0, stream>>>(xw1, Bfrag1, bhh1, hlast);
    tail_kernel<<<dim3(32), 256, 0, stream>>>(f, hlast, fc1Wt, fc1b, fc2W, fc2b, out);
}